// Round 10
// baseline (522.190 us; speedup 1.0000x reference)
//
#include <hip/hip_runtime.h>

#define NNODE 500000
#define NEDGE 8000000

#define LOCALN 512                    // nodes per bucket (power of 2)
#define NBUCKET 977                   // ceil(500000 / 512)
#define EPB 32768                     // edges per scatter block
#define NBLK 245                      // ceil(NEDGE / EPB)
#define SEG 8698                      // per-bucket payload segment (mean 8188 + 5.6σ;
                                      // expected max over 977 buckets ≈ 8524)

// scatter dynamic LDS: stage[EPB] | lscan[NBUCKET+1] | lcur[NBUCKET]
#define SCATTER_LDS_WORDS (EPB + (NBUCKET + 1) + NBUCKET)
#define SCATTER_LDS_BYTES (SCATTER_LDS_WORDS * 4)

// ---------------------------------------------------------------------------
// init: zero gcur[977] + Wf[16][32] = W_gcn[16][48] @ W1[48][32]
// (one block, 1024 threads; ws is poisoned every call)
// ---------------------------------------------------------------------------
__global__ __launch_bounds__(1024) void init_kernel(int* __restrict__ gcur,
                                                    const float* __restrict__ Wg,
                                                    const float* __restrict__ W1,
                                                    float* __restrict__ Wf) {
    int t = threadIdx.x;
    if (t < NBUCKET) gcur[t] = 0;
    if (t < 512) {
        int r = t >> 5;               // 0..15
        int c = t & 31;               // 0..31
        float s = 0.f;
        #pragma unroll
        for (int k = 0; k < 48; ++k) s += Wg[r * 48 + k] * W1[k * 32 + c];
        Wf[t] = s;
    }
}

// ---------------------------------------------------------------------------
// Scatter: per block, LDS counting sort of its 32K edges (local hist ->
// local scan -> placement into stage[]), then per-bucket-run flush:
// one global atomicAdd reserves the run's slot in bucket k's static segment,
// consecutive lanes write consecutive payload addresses (write amp ~1x).
// payload[k*SEG + ...] = (src << 9) | (dst & 511)
// ---------------------------------------------------------------------------
__global__ __launch_bounds__(1024) void scatter_kernel(const int* __restrict__ src,
                                                       const int* __restrict__ dst,
                                                       int* __restrict__ gcur,
                                                       int* __restrict__ payload) {
    extern __shared__ int smem[];
    int* stage = smem;                       // [EPB]
    int* lscan = smem + EPB;                 // [NBUCKET+1]
    int* lcur  = lscan + (NBUCKET + 1);      // [NBUCKET]

    int t = threadIdx.x, b = blockIdx.x;
    int base = b * EPB;

    // phase 1: local histogram (counts at lscan[1..NBUCKET])
    for (int k = t; k <= NBUCKET; k += 1024) lscan[k] = 0;
    __syncthreads();
    #pragma unroll
    for (int i = 0; i < EPB / 1024; ++i) {
        int e = base + i * 1024 + t;
        if (e < NEDGE) atomicAdd(&lscan[1 + (dst[e] >> 9)], 1);
    }
    __syncthreads();

    // phase 2: inclusive scan over lscan[1..NBUCKET] -> lscan[k] = local start
    #pragma unroll
    for (int off = 1; off < NBUCKET; off <<= 1) {
        int x = 0;
        if (t < NBUCKET && t >= off) x = lscan[t + 1 - off];
        __syncthreads();
        if (t < NBUCKET) lscan[t + 1] += x;
        __syncthreads();
    }
    for (int k = t; k < NBUCKET; k += 1024) lcur[k] = lscan[k];
    __syncthreads();

    // phase 3: placement into LDS stage
    #pragma unroll
    for (int i = 0; i < EPB / 1024; ++i) {
        int e = base + i * 1024 + t;
        if (e < NEDGE) {
            int s = src[e];
            int d = dst[e];
            int k = d >> 9;
            int r = atomicAdd(&lcur[k], 1);
            stage[r] = (s << 9) | (d & 511);
        }
    }
    __syncthreads();

    // phase 4: run flush. lane 0 reserves the run slot; wave writes coalesced.
    int wid = t >> 6, lane = t & 63;
    for (int k = wid; k < NBUCKET; k += 16) {
        int s0  = lscan[k];
        int len = lscan[k + 1] - s0;
        int gb = 0;
        if (lane == 0 && len > 0) gb = atomicAdd(&gcur[k], len);
        gb = __shfl(gb, 0);
        if (len > 0) {
            int lim = SEG - gb;                    // clamp (prob ~0 overflow)
            if (lim < len) len = (lim > 0) ? lim : 0;
            int* dstp = payload + (size_t)k * SEG + gb;
            for (int off = lane; off < len; off += 64)
                dstp[off] = stage[s0 + off];
        }
    }
}

// ---------------------------------------------------------------------------
// dinv: per-bucket degree histogram -> dinv
// ---------------------------------------------------------------------------
__global__ __launch_bounds__(512) void dinv_kernel(const int* __restrict__ payload,
                                                   const int* __restrict__ gcur,
                                                   float* __restrict__ dinv) {
    __shared__ int h[LOCALN];
    int t = threadIdx.x, k = blockIdx.x;
    h[t] = 0;
    __syncthreads();
    int n = gcur[k]; if (n > SEG) n = SEG;
    const int* seg = payload + (size_t)k * SEG;
    for (int e = t; e < n; e += 512) atomicAdd(&h[seg[e] & 511], 1);
    __syncthreads();
    int node = k * LOCALN + t;
    if (node < NNODE) dinv[node] = rsqrtf((float)(h[t] + 1));   // +1 self-loop
}

// ---------------------------------------------------------------------------
// Gather: per-bucket LDS counting sort + register pull-gather + fused MLP.
// 1024 threads = 64 groups x 16 lanes.
// ---------------------------------------------------------------------------
__global__ __launch_bounds__(1024) void gather_kernel(
        const float* __restrict__ xx, const int* __restrict__ payload,
        const int* __restrict__ gcur, const float* __restrict__ dinv,
        const float* __restrict__ Wf, const float* __restrict__ b1,
        const float* __restrict__ W2, const float* __restrict__ b2,
        float* __restrict__ out) {
    __shared__ int   srt[SEG];
    __shared__ int   nb[LOCALN + 1];
    __shared__ int   cur[LOCALN];
    __shared__ float sWf[512];
    __shared__ float sW2[512];
    __shared__ float sb1[32];
    __shared__ float sb2[16];

    int t = threadIdx.x, k = blockIdx.x;
    if (t < 512) { sWf[t] = Wf[t]; sW2[t] = W2[t]; }
    if (t < 32) sb1[t] = b1[t];
    if (t < 16) sb2[t] = b2[t];
    if (t <= LOCALN) nb[t] = 0;
    __syncthreads();

    int n = gcur[k]; if (n > SEG) n = SEG;
    const int* seg = payload + (size_t)k * SEG;

    // pass 1: local degree histogram (counts at nb[1..512])
    for (int e = t; e < n; e += 1024) atomicAdd(&nb[(seg[e] & 511) + 1], 1);
    __syncthreads();

    // inclusive scan over nb[1..512] -> nb[i] = local row start of node i
    #pragma unroll
    for (int off = 1; off < 512; off <<= 1) {
        int x = 0;
        if (t < 512 && t >= off) x = nb[t + 1 - off];
        __syncthreads();
        if (t < 512) nb[t + 1] += x;
        __syncthreads();
    }
    if (t < LOCALN) cur[t] = nb[t];
    __syncthreads();

    // pass 2: place src indices by local dst (seg re-read is L2-hot)
    for (int e = t; e < n; e += 1024) {
        int p = seg[e];
        int r = atomicAdd(&cur[p & 511], 1);
        srt[r] = p >> 9;
    }
    __syncthreads();

    int g = t >> 4;                 // group 0..63
    int c = t & 15;                 // channel

    #pragma unroll 1
    for (int q = 0; q < LOCALN / 64; ++q) {
        int local = q * 64 + g;     // wave's 4 groups -> 4 consecutive nodes
        int node = k * LOCALN + local;
        if (node < NNODE) {
            float di = dinv[node];
            float xv = xx[(size_t)node * 16 + c];
            float acc = xv * di;    // self-loop term

            int j = nb[local], jend = nb[local + 1];
            for (; j + 4 <= jend; j += 4) {
                int s0 = srt[j], s1 = srt[j + 1], s2 = srt[j + 2], s3 = srt[j + 3];
                float d0 = dinv[s0], d1 = dinv[s1], d2 = dinv[s2], d3 = dinv[s3];
                float v0 = xx[(size_t)s0 * 16 + c];
                float v1 = xx[(size_t)s1 * 16 + c];
                float v2 = xx[(size_t)s2 * 16 + c];
                float v3 = xx[(size_t)s3 * 16 + c];
                acc = fmaf(v0, d0, acc);
                acc = fmaf(v1, d1, acc);
                acc = fmaf(v2, d2, acc);
                acc = fmaf(v3, d3, acc);
            }
            for (; j < jend; ++j) {
                int s = srt[j];
                acc = fmaf(xx[(size_t)s * 16 + c], dinv[s], acc);
            }

            float a = di * acc;

            // hidden layer: lane c computes units c and c+16
            float h0 = sb1[c], h1 = sb1[c + 16];
            #pragma unroll
            for (int kk = 0; kk < 16; ++kk) {
                float av = __shfl(a, kk, 16);
                h0 = fmaf(av, sWf[kk * 32 + c], h0);
                h1 = fmaf(av, sWf[kk * 32 + c + 16], h1);
            }
            h0 = fmaxf(h0, 0.f);
            h1 = fmaxf(h1, 0.f);

            float u = sb2[c];
            #pragma unroll
            for (int jj = 0; jj < 16; ++jj) {
                float hv0 = __shfl(h0, jj, 16);
                float hv1 = __shfl(h1, jj, 16);
                u = fmaf(hv0, sW2[jj * 16 + c], u);
                u = fmaf(hv1, sW2[(jj + 16) * 16 + c], u);
            }

            out[(size_t)node * 16 + c] = xv + u;
        }
    }
}

extern "C" void kernel_launch(void* const* d_in, const int* in_sizes, int n_in,
                              void* d_out, int out_size, void* d_ws, size_t ws_size,
                              hipStream_t stream) {
    const float* xx   = (const float*)d_in[0];
    const int*   edge = (const int*)d_in[1];   // [2, E]: row0 = src, row1 = dst
    const float* Wg   = (const float*)d_in[2];
    const float* W1   = (const float*)d_in[3];
    const float* b1   = (const float*)d_in[4];
    const float* W2   = (const float*)d_in[5];
    const float* b2   = (const float*)d_in[6];
    float* out = (float*)d_out;

    const int* srcI = edge;
    const int* dstI = edge + NEDGE;

    // workspace (4B words):
    // payload[NBUCKET*SEG = 8,497,946] | gcur[977] | dinv[500000] | Wf[512]
    // total = 8,999,435 words <= 9,000,512 available
    int*   ws      = (int*)d_ws;
    int*   payload = ws;
    int*   gcur    = ws + (size_t)NBUCKET * SEG;
    float* dinv    = (float*)(gcur + NBUCKET);
    float* Wf      = dinv + NNODE;

    // allow >64KB dynamic LDS for the staging scatter (one-time attribute set)
    static bool lds_attr_set = false;
    if (!lds_attr_set) {
        hipFuncSetAttribute((const void*)scatter_kernel,
                            hipFuncAttributeMaxDynamicSharedMemorySize,
                            SCATTER_LDS_BYTES);
        lds_attr_set = true;
    }

    hipLaunchKernelGGL(init_kernel, dim3(1), dim3(1024), 0, stream,
                       gcur, Wg, W1, Wf);

    hipLaunchKernelGGL(scatter_kernel, dim3(NBLK), dim3(1024), SCATTER_LDS_BYTES,
                       stream, srcI, dstI, gcur, payload);

    hipLaunchKernelGGL(dinv_kernel, dim3(NBUCKET), dim3(512), 0, stream,
                       payload, gcur, dinv);

    hipLaunchKernelGGL(gather_kernel, dim3(NBUCKET), dim3(1024), 0, stream,
                       xx, payload, gcur, dinv, Wf, b1, W2, b2, out);
}

// Round 13
// 380.328 us; speedup vs baseline: 1.3730x; 1.3730x over previous
//
#include <hip/hip_runtime.h>

#define NNODE 500000
#define NEDGE 8000000

#define LOCALN 512                    // nodes per bucket (power of 2)
#define NBUCKET 977                   // ceil(500000 / 512)
#define EPB 32768                     // edges per scatter block
#define NBLK 245                      // ceil(NEDGE / EPB)
#define SEG 8698                      // per-bucket payload segment (mean 8188 + 5.6σ)

// scatter dynamic LDS: stage[EPB] | lscan[NBUCKET+1] | lcur[NBUCKET] | gbase[NBUCKET]
#define SCATTER_LDS_WORDS (EPB + (NBUCKET + 1) + NBUCKET + NBUCKET)
#define SCATTER_LDS_BYTES (SCATTER_LDS_WORDS * 4)

// ---------------------------------------------------------------------------
// init: zero gcur[977] + Wf[16][32] = W_gcn[16][48] @ W1[48][32]
// (one block, 1024 threads; ws is poisoned every call)
// ---------------------------------------------------------------------------
__global__ __launch_bounds__(1024) void init_kernel(int* __restrict__ gcur,
                                                    const float* __restrict__ Wg,
                                                    const float* __restrict__ W1,
                                                    float* __restrict__ Wf) {
    int t = threadIdx.x;
    if (t < NBUCKET) gcur[t] = 0;
    if (t < 512) {
        int r = t >> 5;               // 0..15
        int c = t & 31;               // 0..31
        float s = 0.f;
        #pragma unroll
        for (int k = 0; k < 48; ++k) s += Wg[r * 48 + k] * W1[k * 32 + c];
        Wf[t] = s;
    }
}

// ---------------------------------------------------------------------------
// Scatter: per block, LDS counting sort of its 32K edges (local hist ->
// local scan -> BATCHED global reservation -> placement -> run flush).
// Reservation: thread t<977 does ONE atomicAdd for bucket t (all 977 issued
// wave-parallel; latency overlaps the placement phase). Flush: consecutive
// lanes write consecutive payload addresses (write amp ~1x).
// payload[k*SEG + ...] = (src << 9) | (dst & 511)
// ---------------------------------------------------------------------------
__global__ __launch_bounds__(1024) void scatter_kernel(const int* __restrict__ src,
                                                       const int* __restrict__ dst,
                                                       int* __restrict__ gcur,
                                                       int* __restrict__ payload) {
    extern __shared__ int smem[];
    int* stage = smem;                       // [EPB]
    int* lscan = smem + EPB;                 // [NBUCKET+1]
    int* lcur  = lscan + (NBUCKET + 1);      // [NBUCKET]
    int* gbase = lcur + NBUCKET;             // [NBUCKET]

    int t = threadIdx.x, b = blockIdx.x;
    int base = b * EPB;

    // phase 1: local histogram (counts at lscan[1..NBUCKET])
    for (int k = t; k <= NBUCKET; k += 1024) lscan[k] = 0;
    __syncthreads();
    #pragma unroll
    for (int i = 0; i < EPB / 1024; ++i) {
        int e = base + i * 1024 + t;
        if (e < NEDGE) atomicAdd(&lscan[1 + (dst[e] >> 9)], 1);
    }
    __syncthreads();

    // phase 2: inclusive scan over lscan[1..NBUCKET] -> lscan[k] = local start
    #pragma unroll
    for (int off = 1; off < NBUCKET; off <<= 1) {
        int x = 0;
        if (t < NBUCKET && t >= off) x = lscan[t + 1 - off];
        __syncthreads();
        if (t < NBUCKET) lscan[t + 1] += x;
        __syncthreads();
    }

    // phase 2.5: batched reservation (one vector atomic, latency hidden
    // under phase 3) + cursor init
    if (t < NBUCKET) {
        int len = lscan[t + 1] - lscan[t];
        gbase[t] = atomicAdd(&gcur[t], len);
        lcur[t]  = lscan[t];
    }
    __syncthreads();

    // phase 3: placement into LDS stage
    #pragma unroll
    for (int i = 0; i < EPB / 1024; ++i) {
        int e = base + i * 1024 + t;
        if (e < NEDGE) {
            int s = src[e];
            int d = dst[e];
            int k = d >> 9;
            int r = atomicAdd(&lcur[k], 1);
            stage[r] = (s << 9) | (d & 511);
        }
    }
    __syncthreads();

    // phase 4: run flush from precomputed bases (no atomics, no shfl)
    int wid = t >> 6, lane = t & 63;
    for (int k = wid; k < NBUCKET; k += 16) {
        int s0  = lscan[k];
        int len = lscan[k + 1] - s0;
        if (len > 0) {
            int gb  = gbase[k];
            int lim = SEG - gb;                    // clamp (prob ~0 overflow)
            if (lim < len) len = (lim > 0) ? lim : 0;
            int* dstp = payload + (size_t)k * SEG + gb;
            for (int off = lane; off < len; off += 64)
                dstp[off] = stage[s0 + off];
        }
    }
}

// ---------------------------------------------------------------------------
// dinv: per-bucket degree histogram -> dinv
// ---------------------------------------------------------------------------
__global__ __launch_bounds__(512) void dinv_kernel(const int* __restrict__ payload,
                                                   const int* __restrict__ gcur,
                                                   float* __restrict__ dinv) {
    __shared__ int h[LOCALN];
    int t = threadIdx.x, k = blockIdx.x;
    h[t] = 0;
    __syncthreads();
    int n = gcur[k]; if (n > SEG) n = SEG;
    const int* seg = payload + (size_t)k * SEG;
    for (int e = t; e < n; e += 512) atomicAdd(&h[seg[e] & 511], 1);
    __syncthreads();
    int node = k * LOCALN + t;
    if (node < NNODE) dinv[node] = rsqrtf((float)(h[t] + 1));   // +1 self-loop
}

// ---------------------------------------------------------------------------
// Gather: per-bucket LDS counting sort + register pull-gather + fused MLP.
// 1024 threads = 64 groups x 16 lanes.
// ---------------------------------------------------------------------------
__global__ __launch_bounds__(1024) void gather_kernel(
        const float* __restrict__ xx, const int* __restrict__ payload,
        const int* __restrict__ gcur, const float* __restrict__ dinv,
        const float* __restrict__ Wf, const float* __restrict__ b1,
        const float* __restrict__ W2, const float* __restrict__ b2,
        float* __restrict__ out) {
    __shared__ int   srt[SEG];
    __shared__ int   nb[LOCALN + 1];
    __shared__ int   cur[LOCALN];
    __shared__ float sWf[512];
    __shared__ float sW2[512];
    __shared__ float sb1[32];
    __shared__ float sb2[16];

    int t = threadIdx.x, k = blockIdx.x;
    if (t < 512) { sWf[t] = Wf[t]; sW2[t] = W2[t]; }
    if (t < 32) sb1[t] = b1[t];
    if (t < 16) sb2[t] = b2[t];
    if (t <= LOCALN) nb[t] = 0;
    __syncthreads();

    int n = gcur[k]; if (n > SEG) n = SEG;
    const int* seg = payload + (size_t)k * SEG;

    // pass 1: local degree histogram (counts at nb[1..512])
    for (int e = t; e < n; e += 1024) atomicAdd(&nb[(seg[e] & 511) + 1], 1);
    __syncthreads();

    // inclusive scan over nb[1..512] -> nb[i] = local row start of node i
    #pragma unroll
    for (int off = 1; off < 512; off <<= 1) {
        int x = 0;
        if (t < 512 && t >= off) x = nb[t + 1 - off];
        __syncthreads();
        if (t < 512) nb[t + 1] += x;
        __syncthreads();
    }
    if (t < LOCALN) cur[t] = nb[t];
    __syncthreads();

    // pass 2: place src indices by local dst (seg re-read is L2-hot)
    for (int e = t; e < n; e += 1024) {
        int p = seg[e];
        int r = atomicAdd(&cur[p & 511], 1);
        srt[r] = p >> 9;
    }
    __syncthreads();

    int g = t >> 4;                 // group 0..63
    int c = t & 15;                 // channel

    #pragma unroll 1
    for (int q = 0; q < LOCALN / 64; ++q) {
        int local = q * 64 + g;     // wave's 4 groups -> 4 consecutive nodes
        int node = k * LOCALN + local;
        if (node < NNODE) {
            float di = dinv[node];
            float xv = xx[(size_t)node * 16 + c];
            float acc = xv * di;    // self-loop term

            int j = nb[local], jend = nb[local + 1];
            for (; j + 4 <= jend; j += 4) {
                int s0 = srt[j], s1 = srt[j + 1], s2 = srt[j + 2], s3 = srt[j + 3];
                float d0 = dinv[s0], d1 = dinv[s1], d2 = dinv[s2], d3 = dinv[s3];
                float v0 = xx[(size_t)s0 * 16 + c];
                float v1 = xx[(size_t)s1 * 16 + c];
                float v2 = xx[(size_t)s2 * 16 + c];
                float v3 = xx[(size_t)s3 * 16 + c];
                acc = fmaf(v0, d0, acc);
                acc = fmaf(v1, d1, acc);
                acc = fmaf(v2, d2, acc);
                acc = fmaf(v3, d3, acc);
            }
            for (; j < jend; ++j) {
                int s = srt[j];
                acc = fmaf(xx[(size_t)s * 16 + c], dinv[s], acc);
            }

            float a = di * acc;

            // hidden layer: lane c computes units c and c+16
            float h0 = sb1[c], h1 = sb1[c + 16];
            #pragma unroll
            for (int kk = 0; kk < 16; ++kk) {
                float av = __shfl(a, kk, 16);
                h0 = fmaf(av, sWf[kk * 32 + c], h0);
                h1 = fmaf(av, sWf[kk * 32 + c + 16], h1);
            }
            h0 = fmaxf(h0, 0.f);
            h1 = fmaxf(h1, 0.f);

            float u = sb2[c];
            #pragma unroll
            for (int jj = 0; jj < 16; ++jj) {
                float hv0 = __shfl(h0, jj, 16);
                float hv1 = __shfl(h1, jj, 16);
                u = fmaf(hv0, sW2[jj * 16 + c], u);
                u = fmaf(hv1, sW2[(jj + 16) * 16 + c], u);
            }

            out[(size_t)node * 16 + c] = xv + u;
        }
    }
}

extern "C" void kernel_launch(void* const* d_in, const int* in_sizes, int n_in,
                              void* d_out, int out_size, void* d_ws, size_t ws_size,
                              hipStream_t stream) {
    const float* xx   = (const float*)d_in[0];
    const int*   edge = (const int*)d_in[1];   // [2, E]: row0 = src, row1 = dst
    const float* Wg   = (const float*)d_in[2];
    const float* W1   = (const float*)d_in[3];
    const float* b1   = (const float*)d_in[4];
    const float* W2   = (const float*)d_in[5];
    const float* b2   = (const float*)d_in[6];
    float* out = (float*)d_out;

    const int* srcI = edge;
    const int* dstI = edge + NEDGE;

    // workspace (4B words):
    // payload[NBUCKET*SEG = 8,497,946] | gcur[977] | dinv[500000] | Wf[512]
    // total = 8,999,435 words <= 9,000,512 available
    int*   ws      = (int*)d_ws;
    int*   payload = ws;
    int*   gcur    = ws + (size_t)NBUCKET * SEG;
    float* dinv    = (float*)(gcur + NBUCKET);
    float* Wf      = dinv + NNODE;

    // allow >64KB dynamic LDS for the staging scatter (one-time attribute set)
    static bool lds_attr_set = false;
    if (!lds_attr_set) {
        hipFuncSetAttribute((const void*)scatter_kernel,
                            hipFuncAttributeMaxDynamicSharedMemorySize,
                            SCATTER_LDS_BYTES);
        lds_attr_set = true;
    }

    hipLaunchKernelGGL(init_kernel, dim3(1), dim3(1024), 0, stream,
                       gcur, Wg, W1, Wf);

    hipLaunchKernelGGL(scatter_kernel, dim3(NBLK), dim3(1024), SCATTER_LDS_BYTES,
                       stream, srcI, dstI, gcur, payload);

    hipLaunchKernelGGL(dinv_kernel, dim3(NBUCKET), dim3(512), 0, stream,
                       payload, gcur, dinv);

    hipLaunchKernelGGL(gather_kernel, dim3(NBUCKET), dim3(1024), 0, stream,
                       xx, payload, gcur, dinv, Wf, b1, W2, b2, out);
}

// Round 14
// 369.981 us; speedup vs baseline: 1.4114x; 1.0280x over previous
//
#include <hip/hip_runtime.h>

#define NNODE 500000
#define NEDGE 8000000

#define LOCALN 512                    // nodes per bucket (power of 2)
#define NBUCKET 977                   // ceil(500000 / 512)
#define EPB 16384                     // edges per scatter block (64KB stage -> 2 blocks/CU)
#define NBLK 489                      // ceil(NEDGE / EPB)
#define SEG 8698                      // per-bucket payload segment (mean 8188 + 5.6σ)

// scatter dynamic LDS: stage[EPB] | lscan[NBUCKET+1] | lcur[NBUCKET] | gbase[NBUCKET]
#define SCATTER_LDS_WORDS (EPB + (NBUCKET + 1) + NBUCKET + NBUCKET)
#define SCATTER_LDS_BYTES (SCATTER_LDS_WORDS * 4)   // 77,264 B -> 2 blocks/CU

// ---------------------------------------------------------------------------
// init: zero gcur[977] + Wf[16][32] = W_gcn[16][48] @ W1[48][32]
// (one block, 1024 threads; ws is poisoned every call)
// ---------------------------------------------------------------------------
__global__ __launch_bounds__(1024) void init_kernel(int* __restrict__ gcur,
                                                    const float* __restrict__ Wg,
                                                    const float* __restrict__ W1,
                                                    float* __restrict__ Wf) {
    int t = threadIdx.x;
    if (t < NBUCKET) gcur[t] = 0;
    if (t < 512) {
        int r = t >> 5;               // 0..15
        int c = t & 31;               // 0..31
        float s = 0.f;
        #pragma unroll
        for (int k = 0; k < 48; ++k) s += Wg[r * 48 + k] * W1[k * 32 + c];
        Wf[t] = s;
    }
}

// ---------------------------------------------------------------------------
// Scatter: per block, LDS counting sort of its 16K edges (local hist ->
// local scan -> BATCHED global reservation -> placement -> run flush).
// EPB=16384 keeps LDS at 77KB -> 2 blocks/CU (50% occupancy) so the
// streaming, scan, and placement phases of co-resident blocks overlap.
// payload[k*SEG + ...] = (src << 9) | (dst & 511)
// ---------------------------------------------------------------------------
__global__ __launch_bounds__(1024) void scatter_kernel(const int* __restrict__ src,
                                                       const int* __restrict__ dst,
                                                       int* __restrict__ gcur,
                                                       int* __restrict__ payload) {
    extern __shared__ int smem[];
    int* stage = smem;                       // [EPB]
    int* lscan = smem + EPB;                 // [NBUCKET+1]
    int* lcur  = lscan + (NBUCKET + 1);      // [NBUCKET]
    int* gbase = lcur + NBUCKET;             // [NBUCKET]

    int t = threadIdx.x, b = blockIdx.x;
    int base = b * EPB;

    // phase 1: local histogram (counts at lscan[1..NBUCKET])
    for (int k = t; k <= NBUCKET; k += 1024) lscan[k] = 0;
    __syncthreads();
    #pragma unroll
    for (int i = 0; i < EPB / 1024; ++i) {
        int e = base + i * 1024 + t;
        if (e < NEDGE) atomicAdd(&lscan[1 + (dst[e] >> 9)], 1);
    }
    __syncthreads();

    // phase 2: inclusive scan over lscan[1..NBUCKET] -> lscan[k] = local start
    #pragma unroll
    for (int off = 1; off < NBUCKET; off <<= 1) {
        int x = 0;
        if (t < NBUCKET && t >= off) x = lscan[t + 1 - off];
        __syncthreads();
        if (t < NBUCKET) lscan[t + 1] += x;
        __syncthreads();
    }

    // phase 2.5: batched reservation (one vector atomic, latency hidden
    // under phase 3) + cursor init
    if (t < NBUCKET) {
        int len = lscan[t + 1] - lscan[t];
        gbase[t] = atomicAdd(&gcur[t], len);
        lcur[t]  = lscan[t];
    }
    __syncthreads();

    // phase 3: placement into LDS stage
    #pragma unroll
    for (int i = 0; i < EPB / 1024; ++i) {
        int e = base + i * 1024 + t;
        if (e < NEDGE) {
            int s = src[e];
            int d = dst[e];
            int k = d >> 9;
            int r = atomicAdd(&lcur[k], 1);
            stage[r] = (s << 9) | (d & 511);
        }
    }
    __syncthreads();

    // phase 4: run flush from precomputed bases (no atomics, no shfl)
    int wid = t >> 6, lane = t & 63;
    for (int k = wid; k < NBUCKET; k += 16) {
        int s0  = lscan[k];
        int len = lscan[k + 1] - s0;
        if (len > 0) {
            int gb  = gbase[k];
            int lim = SEG - gb;                    // clamp (prob ~0 overflow)
            if (lim < len) len = (lim > 0) ? lim : 0;
            int* dstp = payload + (size_t)k * SEG + gb;
            for (int off = lane; off < len; off += 64)
                dstp[off] = stage[s0 + off];
        }
    }
}

// ---------------------------------------------------------------------------
// dinv: per-bucket degree histogram -> dinv
// ---------------------------------------------------------------------------
__global__ __launch_bounds__(512) void dinv_kernel(const int* __restrict__ payload,
                                                   const int* __restrict__ gcur,
                                                   float* __restrict__ dinv) {
    __shared__ int h[LOCALN];
    int t = threadIdx.x, k = blockIdx.x;
    h[t] = 0;
    __syncthreads();
    int n = gcur[k]; if (n > SEG) n = SEG;
    const int* seg = payload + (size_t)k * SEG;
    for (int e = t; e < n; e += 512) atomicAdd(&h[seg[e] & 511], 1);
    __syncthreads();
    int node = k * LOCALN + t;
    if (node < NNODE) dinv[node] = rsqrtf((float)(h[t] + 1));   // +1 self-loop
}

// ---------------------------------------------------------------------------
// Gather: per-bucket LDS counting sort + register pull-gather + fused MLP.
// 1024 threads = 64 groups x 16 lanes.
// ---------------------------------------------------------------------------
__global__ __launch_bounds__(1024) void gather_kernel(
        const float* __restrict__ xx, const int* __restrict__ payload,
        const int* __restrict__ gcur, const float* __restrict__ dinv,
        const float* __restrict__ Wf, const float* __restrict__ b1,
        const float* __restrict__ W2, const float* __restrict__ b2,
        float* __restrict__ out) {
    __shared__ int   srt[SEG];
    __shared__ int   nb[LOCALN + 1];
    __shared__ int   cur[LOCALN];
    __shared__ float sWf[512];
    __shared__ float sW2[512];
    __shared__ float sb1[32];
    __shared__ float sb2[16];

    int t = threadIdx.x, k = blockIdx.x;
    if (t < 512) { sWf[t] = Wf[t]; sW2[t] = W2[t]; }
    if (t < 32) sb1[t] = b1[t];
    if (t < 16) sb2[t] = b2[t];
    if (t <= LOCALN) nb[t] = 0;
    __syncthreads();

    int n = gcur[k]; if (n > SEG) n = SEG;
    const int* seg = payload + (size_t)k * SEG;

    // pass 1: local degree histogram (counts at nb[1..512])
    for (int e = t; e < n; e += 1024) atomicAdd(&nb[(seg[e] & 511) + 1], 1);
    __syncthreads();

    // inclusive scan over nb[1..512] -> nb[i] = local row start of node i
    #pragma unroll
    for (int off = 1; off < 512; off <<= 1) {
        int x = 0;
        if (t < 512 && t >= off) x = nb[t + 1 - off];
        __syncthreads();
        if (t < 512) nb[t + 1] += x;
        __syncthreads();
    }
    if (t < LOCALN) cur[t] = nb[t];
    __syncthreads();

    // pass 2: place src indices by local dst (seg re-read is L2-hot)
    for (int e = t; e < n; e += 1024) {
        int p = seg[e];
        int r = atomicAdd(&cur[p & 511], 1);
        srt[r] = p >> 9;
    }
    __syncthreads();

    int g = t >> 4;                 // group 0..63
    int c = t & 15;                 // channel

    #pragma unroll 1
    for (int q = 0; q < LOCALN / 64; ++q) {
        int local = q * 64 + g;     // wave's 4 groups -> 4 consecutive nodes
        int node = k * LOCALN + local;
        if (node < NNODE) {
            float di = dinv[node];
            float xv = xx[(size_t)node * 16 + c];
            float acc = xv * di;    // self-loop term

            int j = nb[local], jend = nb[local + 1];
            for (; j + 4 <= jend; j += 4) {
                int s0 = srt[j], s1 = srt[j + 1], s2 = srt[j + 2], s3 = srt[j + 3];
                float d0 = dinv[s0], d1 = dinv[s1], d2 = dinv[s2], d3 = dinv[s3];
                float v0 = xx[(size_t)s0 * 16 + c];
                float v1 = xx[(size_t)s1 * 16 + c];
                float v2 = xx[(size_t)s2 * 16 + c];
                float v3 = xx[(size_t)s3 * 16 + c];
                acc = fmaf(v0, d0, acc);
                acc = fmaf(v1, d1, acc);
                acc = fmaf(v2, d2, acc);
                acc = fmaf(v3, d3, acc);
            }
            for (; j < jend; ++j) {
                int s = srt[j];
                acc = fmaf(xx[(size_t)s * 16 + c], dinv[s], acc);
            }

            float a = di * acc;

            // hidden layer: lane c computes units c and c+16
            float h0 = sb1[c], h1 = sb1[c + 16];
            #pragma unroll
            for (int kk = 0; kk < 16; ++kk) {
                float av = __shfl(a, kk, 16);
                h0 = fmaf(av, sWf[kk * 32 + c], h0);
                h1 = fmaf(av, sWf[kk * 32 + c + 16], h1);
            }
            h0 = fmaxf(h0, 0.f);
            h1 = fmaxf(h1, 0.f);

            float u = sb2[c];
            #pragma unroll
            for (int jj = 0; jj < 16; ++jj) {
                float hv0 = __shfl(h0, jj, 16);
                float hv1 = __shfl(h1, jj, 16);
                u = fmaf(hv0, sW2[jj * 16 + c], u);
                u = fmaf(hv1, sW2[(jj + 16) * 16 + c], u);
            }

            out[(size_t)node * 16 + c] = xv + u;
        }
    }
}

extern "C" void kernel_launch(void* const* d_in, const int* in_sizes, int n_in,
                              void* d_out, int out_size, void* d_ws, size_t ws_size,
                              hipStream_t stream) {
    const float* xx   = (const float*)d_in[0];
    const int*   edge = (const int*)d_in[1];   // [2, E]: row0 = src, row1 = dst
    const float* Wg   = (const float*)d_in[2];
    const float* W1   = (const float*)d_in[3];
    const float* b1   = (const float*)d_in[4];
    const float* W2   = (const float*)d_in[5];
    const float* b2   = (const float*)d_in[6];
    float* out = (float*)d_out;

    const int* srcI = edge;
    const int* dstI = edge + NEDGE;

    // workspace (4B words):
    // payload[NBUCKET*SEG = 8,497,946] | gcur[977] | dinv[500000] | Wf[512]
    // total = 8,999,435 words <= 9,000,512 available
    int*   ws      = (int*)d_ws;
    int*   payload = ws;
    int*   gcur    = ws + (size_t)NBUCKET * SEG;
    float* dinv    = (float*)(gcur + NBUCKET);
    float* Wf      = dinv + NNODE;

    // allow >64KB dynamic LDS for the staging scatter (one-time attribute set)
    static bool lds_attr_set = false;
    if (!lds_attr_set) {
        hipFuncSetAttribute((const void*)scatter_kernel,
                            hipFuncAttributeMaxDynamicSharedMemorySize,
                            SCATTER_LDS_BYTES);
        lds_attr_set = true;
    }

    hipLaunchKernelGGL(init_kernel, dim3(1), dim3(1024), 0, stream,
                       gcur, Wg, W1, Wf);

    hipLaunchKernelGGL(scatter_kernel, dim3(NBLK), dim3(1024), SCATTER_LDS_BYTES,
                       stream, srcI, dstI, gcur, payload);

    hipLaunchKernelGGL(dinv_kernel, dim3(NBUCKET), dim3(512), 0, stream,
                       payload, gcur, dinv);

    hipLaunchKernelGGL(gather_kernel, dim3(NBUCKET), dim3(1024), 0, stream,
                       xx, payload, gcur, dinv, Wf, b1, W2, b2, out);
}

// Round 15
// 355.118 us; speedup vs baseline: 1.4705x; 1.0419x over previous
//
#include <hip/hip_runtime.h>

#define NNODE 500000
#define NEDGE 8000000

#define LOCALN 512                    // nodes per bucket (power of 2)
#define NBUCKET 977                   // ceil(500000 / 512)
#define EPB 16384                     // edges per scatter block (64KB stage -> 2 blocks/CU)
#define NBLK 489                      // ceil(NEDGE / EPB)
#define SEG 8698                      // per-bucket payload segment (mean 8188 + 5.6σ)

// scatter dynamic LDS: stage[EPB] | lscan[NBUCKET+1] | lcur[NBUCKET] | gbase[NBUCKET]
#define SCATTER_LDS_WORDS (EPB + (NBUCKET + 1) + NBUCKET + NBUCKET)
#define SCATTER_LDS_BYTES (SCATTER_LDS_WORDS * 4)   // 77,264 B -> 2 blocks/CU

// ---------------------------------------------------------------------------
// init: zero gcur[977] + Wf[16][32] = W_gcn[16][48] @ W1[48][32]
// (one block, 1024 threads; ws is poisoned every call)
// ---------------------------------------------------------------------------
__global__ __launch_bounds__(1024) void init_kernel(int* __restrict__ gcur,
                                                    const float* __restrict__ Wg,
                                                    const float* __restrict__ W1,
                                                    float* __restrict__ Wf) {
    int t = threadIdx.x;
    if (t < NBUCKET) gcur[t] = 0;
    if (t < 512) {
        int r = t >> 5;               // 0..15
        int c = t & 31;               // 0..31
        float s = 0.f;
        #pragma unroll
        for (int k = 0; k < 48; ++k) s += Wg[r * 48 + k] * W1[k * 32 + c];
        Wf[t] = s;
    }
}

// ---------------------------------------------------------------------------
// Scatter: per block, LDS counting sort of its 16K edges (local hist ->
// local scan -> BATCHED global reservation -> placement -> run flush).
// Flush: 4 buckets per wave (16 lanes each) -> ~full lane efficiency at
// run length ~17 while keeping 64B-chunk contiguity.
// payload[k*SEG + ...] = (src << 9) | (dst & 511)
// ---------------------------------------------------------------------------
__global__ __launch_bounds__(1024) void scatter_kernel(const int* __restrict__ src,
                                                       const int* __restrict__ dst,
                                                       int* __restrict__ gcur,
                                                       int* __restrict__ payload) {
    extern __shared__ int smem[];
    int* stage = smem;                       // [EPB]
    int* lscan = smem + EPB;                 // [NBUCKET+1]
    int* lcur  = lscan + (NBUCKET + 1);      // [NBUCKET]
    int* gbase = lcur + NBUCKET;             // [NBUCKET]

    int t = threadIdx.x, b = blockIdx.x;
    int base = b * EPB;

    // phase 1: local histogram (counts at lscan[1..NBUCKET])
    for (int k = t; k <= NBUCKET; k += 1024) lscan[k] = 0;
    __syncthreads();
    #pragma unroll
    for (int i = 0; i < EPB / 1024; ++i) {
        int e = base + i * 1024 + t;
        if (e < NEDGE) atomicAdd(&lscan[1 + (dst[e] >> 9)], 1);
    }
    __syncthreads();

    // phase 2: inclusive scan over lscan[1..NBUCKET] -> lscan[k] = local start
    #pragma unroll
    for (int off = 1; off < NBUCKET; off <<= 1) {
        int x = 0;
        if (t < NBUCKET && t >= off) x = lscan[t + 1 - off];
        __syncthreads();
        if (t < NBUCKET) lscan[t + 1] += x;
        __syncthreads();
    }

    // phase 2.5: batched reservation (one vector atomic, latency hidden
    // under phase 3) + cursor init
    if (t < NBUCKET) {
        int len = lscan[t + 1] - lscan[t];
        gbase[t] = atomicAdd(&gcur[t], len);
        lcur[t]  = lscan[t];
    }
    __syncthreads();

    // phase 3: placement into LDS stage
    #pragma unroll
    for (int i = 0; i < EPB / 1024; ++i) {
        int e = base + i * 1024 + t;
        if (e < NEDGE) {
            int s = src[e];
            int d = dst[e];
            int k = d >> 9;
            int r = atomicAdd(&lcur[k], 1);
            stage[r] = (s << 9) | (d & 511);
        }
    }
    __syncthreads();

    // phase 4: run flush, 4 buckets/wave x 16 lanes each (no atomics)
    int wid = t >> 6, lane = t & 63;
    int sg  = lane >> 4, l16 = lane & 15;    // subgroup 0..3, lane-in-subgroup
    for (int k = wid * 4 + sg; k < NBUCKET; k += 64) {
        int s0  = lscan[k];
        int len = lscan[k + 1] - s0;
        if (len > 0) {
            int gb  = gbase[k];
            int lim = SEG - gb;                    // clamp (prob ~0 overflow)
            if (lim < len) len = (lim > 0) ? lim : 0;
            int* dstp = payload + (size_t)k * SEG + gb;
            for (int off = l16; off < len; off += 16)
                dstp[off] = stage[s0 + off];
        }
    }
}

// ---------------------------------------------------------------------------
// dinv: per-bucket degree histogram -> dinv (1024 threads)
// ---------------------------------------------------------------------------
__global__ __launch_bounds__(1024) void dinv_kernel(const int* __restrict__ payload,
                                                    const int* __restrict__ gcur,
                                                    float* __restrict__ dinv) {
    __shared__ int h[LOCALN];
    int t = threadIdx.x, k = blockIdx.x;
    if (t < LOCALN) h[t] = 0;
    __syncthreads();
    int n = gcur[k]; if (n > SEG) n = SEG;
    const int* seg = payload + (size_t)k * SEG;
    for (int e = t; e < n; e += 1024) atomicAdd(&h[seg[e] & 511], 1);
    __syncthreads();
    int node = k * LOCALN + t;
    if (t < LOCALN && node < NNODE)
        dinv[node] = rsqrtf((float)(h[t] + 1));   // +1 self-loop
}

// ---------------------------------------------------------------------------
// Gather: per-bucket LDS counting sort + register pull-gather + fused MLP.
// 1024 threads = 64 groups x 16 lanes. Edge walk 8-unrolled for MLP depth.
// ---------------------------------------------------------------------------
__global__ __launch_bounds__(1024) void gather_kernel(
        const float* __restrict__ xx, const int* __restrict__ payload,
        const int* __restrict__ gcur, const float* __restrict__ dinv,
        const float* __restrict__ Wf, const float* __restrict__ b1,
        const float* __restrict__ W2, const float* __restrict__ b2,
        float* __restrict__ out) {
    __shared__ int   srt[SEG];
    __shared__ int   nb[LOCALN + 1];
    __shared__ int   cur[LOCALN];
    __shared__ float sWf[512];
    __shared__ float sW2[512];
    __shared__ float sb1[32];
    __shared__ float sb2[16];

    int t = threadIdx.x, k = blockIdx.x;
    if (t < 512) { sWf[t] = Wf[t]; sW2[t] = W2[t]; }
    if (t < 32) sb1[t] = b1[t];
    if (t < 16) sb2[t] = b2[t];
    if (t <= LOCALN) nb[t] = 0;
    __syncthreads();

    int n = gcur[k]; if (n > SEG) n = SEG;
    const int* seg = payload + (size_t)k * SEG;

    // pass 1: local degree histogram (counts at nb[1..512])
    for (int e = t; e < n; e += 1024) atomicAdd(&nb[(seg[e] & 511) + 1], 1);
    __syncthreads();

    // inclusive scan over nb[1..512] -> nb[i] = local row start of node i
    #pragma unroll
    for (int off = 1; off < 512; off <<= 1) {
        int x = 0;
        if (t < 512 && t >= off) x = nb[t + 1 - off];
        __syncthreads();
        if (t < 512) nb[t + 1] += x;
        __syncthreads();
    }
    if (t < LOCALN) cur[t] = nb[t];
    __syncthreads();

    // pass 2: place src indices by local dst (seg re-read is L2-hot)
    for (int e = t; e < n; e += 1024) {
        int p = seg[e];
        int r = atomicAdd(&cur[p & 511], 1);
        srt[r] = p >> 9;
    }
    __syncthreads();

    int g = t >> 4;                 // group 0..63
    int c = t & 15;                 // channel

    #pragma unroll 1
    for (int q = 0; q < LOCALN / 64; ++q) {
        int local = q * 64 + g;     // wave's 4 groups -> 4 consecutive nodes
        int node = k * LOCALN + local;
        if (node < NNODE) {
            float di = dinv[node];
            float xv = xx[(size_t)node * 16 + c];
            float acc = xv * di;    // self-loop term

            int j = nb[local], jend = nb[local + 1];
            for (; j + 8 <= jend; j += 8) {
                int s0 = srt[j],     s1 = srt[j + 1], s2 = srt[j + 2], s3 = srt[j + 3];
                int s4 = srt[j + 4], s5 = srt[j + 5], s6 = srt[j + 6], s7 = srt[j + 7];
                float d0 = dinv[s0], d1 = dinv[s1], d2 = dinv[s2], d3 = dinv[s3];
                float d4 = dinv[s4], d5 = dinv[s5], d6 = dinv[s6], d7 = dinv[s7];
                float v0 = xx[(size_t)s0 * 16 + c];
                float v1 = xx[(size_t)s1 * 16 + c];
                float v2 = xx[(size_t)s2 * 16 + c];
                float v3 = xx[(size_t)s3 * 16 + c];
                float v4 = xx[(size_t)s4 * 16 + c];
                float v5 = xx[(size_t)s5 * 16 + c];
                float v6 = xx[(size_t)s6 * 16 + c];
                float v7 = xx[(size_t)s7 * 16 + c];
                acc = fmaf(v0, d0, acc);
                acc = fmaf(v1, d1, acc);
                acc = fmaf(v2, d2, acc);
                acc = fmaf(v3, d3, acc);
                acc = fmaf(v4, d4, acc);
                acc = fmaf(v5, d5, acc);
                acc = fmaf(v6, d6, acc);
                acc = fmaf(v7, d7, acc);
            }
            for (; j + 4 <= jend; j += 4) {
                int s0 = srt[j], s1 = srt[j + 1], s2 = srt[j + 2], s3 = srt[j + 3];
                float d0 = dinv[s0], d1 = dinv[s1], d2 = dinv[s2], d3 = dinv[s3];
                float v0 = xx[(size_t)s0 * 16 + c];
                float v1 = xx[(size_t)s1 * 16 + c];
                float v2 = xx[(size_t)s2 * 16 + c];
                float v3 = xx[(size_t)s3 * 16 + c];
                acc = fmaf(v0, d0, acc);
                acc = fmaf(v1, d1, acc);
                acc = fmaf(v2, d2, acc);
                acc = fmaf(v3, d3, acc);
            }
            for (; j < jend; ++j) {
                int s = srt[j];
                acc = fmaf(xx[(size_t)s * 16 + c], dinv[s], acc);
            }

            float a = di * acc;

            // hidden layer: lane c computes units c and c+16
            float h0 = sb1[c], h1 = sb1[c + 16];
            #pragma unroll
            for (int kk = 0; kk < 16; ++kk) {
                float av = __shfl(a, kk, 16);
                h0 = fmaf(av, sWf[kk * 32 + c], h0);
                h1 = fmaf(av, sWf[kk * 32 + c + 16], h1);
            }
            h0 = fmaxf(h0, 0.f);
            h1 = fmaxf(h1, 0.f);

            float u = sb2[c];
            #pragma unroll
            for (int jj = 0; jj < 16; ++jj) {
                float hv0 = __shfl(h0, jj, 16);
                float hv1 = __shfl(h1, jj, 16);
                u = fmaf(hv0, sW2[jj * 16 + c], u);
                u = fmaf(hv1, sW2[(jj + 16) * 16 + c], u);
            }

            out[(size_t)node * 16 + c] = xv + u;
        }
    }
}

extern "C" void kernel_launch(void* const* d_in, const int* in_sizes, int n_in,
                              void* d_out, int out_size, void* d_ws, size_t ws_size,
                              hipStream_t stream) {
    const float* xx   = (const float*)d_in[0];
    const int*   edge = (const int*)d_in[1];   // [2, E]: row0 = src, row1 = dst
    const float* Wg   = (const float*)d_in[2];
    const float* W1   = (const float*)d_in[3];
    const float* b1   = (const float*)d_in[4];
    const float* W2   = (const float*)d_in[5];
    const float* b2   = (const float*)d_in[6];
    float* out = (float*)d_out;

    const int* srcI = edge;
    const int* dstI = edge + NEDGE;

    // workspace (4B words):
    // payload[NBUCKET*SEG = 8,497,946] | gcur[977] | dinv[500000] | Wf[512]
    // total = 8,999,435 words <= 9,000,512 available
    int*   ws      = (int*)d_ws;
    int*   payload = ws;
    int*   gcur    = ws + (size_t)NBUCKET * SEG;
    float* dinv    = (float*)(gcur + NBUCKET);
    float* Wf      = dinv + NNODE;

    // allow >64KB dynamic LDS for the staging scatter (one-time attribute set)
    static bool lds_attr_set = false;
    if (!lds_attr_set) {
        hipFuncSetAttribute((const void*)scatter_kernel,
                            hipFuncAttributeMaxDynamicSharedMemorySize,
                            SCATTER_LDS_BYTES);
        lds_attr_set = true;
    }

    hipLaunchKernelGGL(init_kernel, dim3(1), dim3(1024), 0, stream,
                       gcur, Wg, W1, Wf);

    hipLaunchKernelGGL(scatter_kernel, dim3(NBLK), dim3(1024), SCATTER_LDS_BYTES,
                       stream, srcI, dstI, gcur, payload);

    hipLaunchKernelGGL(dinv_kernel, dim3(NBUCKET), dim3(1024), 0, stream,
                       payload, gcur, dinv);

    hipLaunchKernelGGL(gather_kernel, dim3(NBUCKET), dim3(1024), 0, stream,
                       xx, payload, gcur, dinv, Wf, b1, W2, b2, out);
}

// Round 16
// 348.167 us; speedup vs baseline: 1.4998x; 1.0200x over previous
//
#include <hip/hip_runtime.h>

#define NNODE 500000
#define NEDGE 8000000

#define LOCALN 512                    // nodes per bucket (power of 2)
#define NBUCKET 977                   // ceil(500000 / 512)
#define EPB 16384                     // edges per scatter block (64KB stage -> 2 blocks/CU)
#define NBLK 489                      // ceil(NEDGE / EPB)
#define SEG 8698                      // per-bucket payload segment (mean 8188 + 5.6σ)

// scatter dynamic LDS: stage[EPB] | lscan[NBUCKET+1] | lcur[NBUCKET] | gbase[NBUCKET] | wsum[16]
#define SCATTER_LDS_WORDS (EPB + (NBUCKET + 1) + NBUCKET + NBUCKET + 16)
#define SCATTER_LDS_BYTES (SCATTER_LDS_WORDS * 4)   // 77,328 B -> 2 blocks/CU

// ---------------------------------------------------------------------------
// init: zero gcur[977] + Wf[16][32] = W_gcn[16][48] @ W1[48][32]
// (one block, 1024 threads; ws is poisoned every call)
// ---------------------------------------------------------------------------
__global__ __launch_bounds__(1024) void init_kernel(int* __restrict__ gcur,
                                                    const float* __restrict__ Wg,
                                                    const float* __restrict__ W1,
                                                    float* __restrict__ Wf) {
    int t = threadIdx.x;
    if (t < NBUCKET) gcur[t] = 0;
    if (t < 512) {
        int r = t >> 5;               // 0..15
        int c = t & 31;               // 0..31
        float s = 0.f;
        #pragma unroll
        for (int k = 0; k < 48; ++k) s += Wg[r * 48 + k] * W1[k * 32 + c];
        Wf[t] = s;
    }
}

// ---------------------------------------------------------------------------
// Scatter: per block, LDS counting sort of its 16K edges.
// Issue-efficiency version: int4 loads (4 edges/load -> 4 independent LDS
// atomics back-to-back, 4x latency overlap), wave-shuffle scan (3 barriers
// instead of 20), batched global reservation, 4-buckets/wave flush.
// payload[k*SEG + ...] = (src << 9) | (dst & 511)
// ---------------------------------------------------------------------------
__global__ __launch_bounds__(1024) void scatter_kernel(const int* __restrict__ src,
                                                       const int* __restrict__ dst,
                                                       int* __restrict__ gcur,
                                                       int* __restrict__ payload) {
    extern __shared__ int smem[];
    int* stage = smem;                       // [EPB]
    int* lscan = smem + EPB;                 // [NBUCKET+1]
    int* lcur  = lscan + (NBUCKET + 1);      // [NBUCKET]
    int* gbase = lcur + NBUCKET;             // [NBUCKET]
    int* wsum  = gbase + NBUCKET;            // [16]

    int t = threadIdx.x, b = blockIdx.x;
    int base = b * EPB;
    int b4 = base >> 2;
    const int4* src4 = (const int4*)src;
    const int4* dst4 = (const int4*)dst;

    // phase 1: local histogram via int4 loads (counts at lscan[1..NBUCKET])
    for (int k = t; k <= NBUCKET; k += 1024) lscan[k] = 0;
    __syncthreads();
    #pragma unroll
    for (int i = 0; i < EPB / 4096; ++i) {   // 4 iterations
        int idx = i * 1024 + t;
        if ((size_t)(base + idx * 4) < NEDGE) {   // NEDGE % 4 == 0
            int4 d4 = dst4[b4 + idx];
            atomicAdd(&lscan[1 + (d4.x >> 9)], 1);
            atomicAdd(&lscan[1 + (d4.y >> 9)], 1);
            atomicAdd(&lscan[1 + (d4.z >> 9)], 1);
            atomicAdd(&lscan[1 + (d4.w >> 9)], 1);
        }
    }
    __syncthreads();

    // phase 2: inclusive scan over lscan[1..NBUCKET] via wave shuffles
    {
        int lane = t & 63, w = t >> 6;
        int v = (t < NBUCKET) ? lscan[t + 1] : 0;
        #pragma unroll
        for (int off = 1; off < 64; off <<= 1) {
            int x = __shfl_up(v, off, 64);
            if (lane >= off) v += x;
        }
        if (lane == 63) wsum[w] = v;
        __syncthreads();
        if (w == 0 && lane < 16) {
            int x = wsum[lane];
            #pragma unroll
            for (int off = 1; off < 16; off <<= 1) {
                int y = __shfl_up(x, off, 16);
                if (lane >= off) x += y;
            }
            wsum[lane] = x;
        }
        __syncthreads();
        int add = (w > 0) ? wsum[w - 1] : 0;
        if (t < NBUCKET) lscan[t + 1] = v + add;
    }
    __syncthreads();

    // phase 2.5: batched reservation (one vector atomic, latency hidden
    // under phase 3) + cursor init
    if (t < NBUCKET) {
        int len = lscan[t + 1] - lscan[t];
        gbase[t] = atomicAdd(&gcur[t], len);
        lcur[t]  = lscan[t];
    }
    __syncthreads();

    // phase 3: placement via int4 loads; 4 independent returning atomics
    #pragma unroll
    for (int i = 0; i < EPB / 4096; ++i) {   // 4 iterations
        int idx = i * 1024 + t;
        if ((size_t)(base + idx * 4) < NEDGE) {
            int4 s4 = src4[b4 + idx];
            int4 d4 = dst4[b4 + idx];
            int r0 = atomicAdd(&lcur[d4.x >> 9], 1);
            int r1 = atomicAdd(&lcur[d4.y >> 9], 1);
            int r2 = atomicAdd(&lcur[d4.z >> 9], 1);
            int r3 = atomicAdd(&lcur[d4.w >> 9], 1);
            stage[r0] = (s4.x << 9) | (d4.x & 511);
            stage[r1] = (s4.y << 9) | (d4.y & 511);
            stage[r2] = (s4.z << 9) | (d4.z & 511);
            stage[r3] = (s4.w << 9) | (d4.w & 511);
        }
    }
    __syncthreads();

    // phase 4: run flush, 4 buckets/wave x 16 lanes each (no atomics)
    int wid = t >> 6, lane = t & 63;
    int sg  = lane >> 4, l16 = lane & 15;    // subgroup 0..3, lane-in-subgroup
    for (int k = wid * 4 + sg; k < NBUCKET; k += 64) {
        int s0  = lscan[k];
        int len = lscan[k + 1] - s0;
        if (len > 0) {
            int gb  = gbase[k];
            int lim = SEG - gb;                    // clamp (prob ~0 overflow)
            if (lim < len) len = (lim > 0) ? lim : 0;
            int* dstp = payload + (size_t)k * SEG + gb;
            for (int off = l16; off < len; off += 16)
                dstp[off] = stage[s0 + off];
        }
    }
}

// ---------------------------------------------------------------------------
// dinv: per-bucket degree histogram -> dinv (1024 threads)
// ---------------------------------------------------------------------------
__global__ __launch_bounds__(1024) void dinv_kernel(const int* __restrict__ payload,
                                                    const int* __restrict__ gcur,
                                                    float* __restrict__ dinv) {
    __shared__ int h[LOCALN];
    int t = threadIdx.x, k = blockIdx.x;
    if (t < LOCALN) h[t] = 0;
    __syncthreads();
    int n = gcur[k]; if (n > SEG) n = SEG;
    const int* seg = payload + (size_t)k * SEG;
    for (int e = t; e < n; e += 1024) atomicAdd(&h[seg[e] & 511], 1);
    __syncthreads();
    int node = k * LOCALN + t;
    if (t < LOCALN && node < NNODE)
        dinv[node] = rsqrtf((float)(h[t] + 1));   // +1 self-loop
}

// ---------------------------------------------------------------------------
// Gather: per-bucket LDS counting sort + register pull-gather + fused MLP.
// 1024 threads = 64 groups x 16 lanes. (byte-identical to round-15 control)
// ---------------------------------------------------------------------------
__global__ __launch_bounds__(1024) void gather_kernel(
        const float* __restrict__ xx, const int* __restrict__ payload,
        const int* __restrict__ gcur, const float* __restrict__ dinv,
        const float* __restrict__ Wf, const float* __restrict__ b1,
        const float* __restrict__ W2, const float* __restrict__ b2,
        float* __restrict__ out) {
    __shared__ int   srt[SEG];
    __shared__ int   nb[LOCALN + 1];
    __shared__ int   cur[LOCALN];
    __shared__ float sWf[512];
    __shared__ float sW2[512];
    __shared__ float sb1[32];
    __shared__ float sb2[16];

    int t = threadIdx.x, k = blockIdx.x;
    if (t < 512) { sWf[t] = Wf[t]; sW2[t] = W2[t]; }
    if (t < 32) sb1[t] = b1[t];
    if (t < 16) sb2[t] = b2[t];
    if (t <= LOCALN) nb[t] = 0;
    __syncthreads();

    int n = gcur[k]; if (n > SEG) n = SEG;
    const int* seg = payload + (size_t)k * SEG;

    // pass 1: local degree histogram (counts at nb[1..512])
    for (int e = t; e < n; e += 1024) atomicAdd(&nb[(seg[e] & 511) + 1], 1);
    __syncthreads();

    // inclusive scan over nb[1..512] -> nb[i] = local row start of node i
    #pragma unroll
    for (int off = 1; off < 512; off <<= 1) {
        int x = 0;
        if (t < 512 && t >= off) x = nb[t + 1 - off];
        __syncthreads();
        if (t < 512) nb[t + 1] += x;
        __syncthreads();
    }
    if (t < LOCALN) cur[t] = nb[t];
    __syncthreads();

    // pass 2: place src indices by local dst (seg re-read is L2-hot)
    for (int e = t; e < n; e += 1024) {
        int p = seg[e];
        int r = atomicAdd(&cur[p & 511], 1);
        srt[r] = p >> 9;
    }
    __syncthreads();

    int g = t >> 4;                 // group 0..63
    int c = t & 15;                 // channel

    #pragma unroll 1
    for (int q = 0; q < LOCALN / 64; ++q) {
        int local = q * 64 + g;     // wave's 4 groups -> 4 consecutive nodes
        int node = k * LOCALN + local;
        if (node < NNODE) {
            float di = dinv[node];
            float xv = xx[(size_t)node * 16 + c];
            float acc = xv * di;    // self-loop term

            int j = nb[local], jend = nb[local + 1];
            for (; j + 8 <= jend; j += 8) {
                int s0 = srt[j],     s1 = srt[j + 1], s2 = srt[j + 2], s3 = srt[j + 3];
                int s4 = srt[j + 4], s5 = srt[j + 5], s6 = srt[j + 6], s7 = srt[j + 7];
                float d0 = dinv[s0], d1 = dinv[s1], d2 = dinv[s2], d3 = dinv[s3];
                float d4 = dinv[s4], d5 = dinv[s5], d6 = dinv[s6], d7 = dinv[s7];
                float v0 = xx[(size_t)s0 * 16 + c];
                float v1 = xx[(size_t)s1 * 16 + c];
                float v2 = xx[(size_t)s2 * 16 + c];
                float v3 = xx[(size_t)s3 * 16 + c];
                float v4 = xx[(size_t)s4 * 16 + c];
                float v5 = xx[(size_t)s5 * 16 + c];
                float v6 = xx[(size_t)s6 * 16 + c];
                float v7 = xx[(size_t)s7 * 16 + c];
                acc = fmaf(v0, d0, acc);
                acc = fmaf(v1, d1, acc);
                acc = fmaf(v2, d2, acc);
                acc = fmaf(v3, d3, acc);
                acc = fmaf(v4, d4, acc);
                acc = fmaf(v5, d5, acc);
                acc = fmaf(v6, d6, acc);
                acc = fmaf(v7, d7, acc);
            }
            for (; j + 4 <= jend; j += 4) {
                int s0 = srt[j], s1 = srt[j + 1], s2 = srt[j + 2], s3 = srt[j + 3];
                float d0 = dinv[s0], d1 = dinv[s1], d2 = dinv[s2], d3 = dinv[s3];
                float v0 = xx[(size_t)s0 * 16 + c];
                float v1 = xx[(size_t)s1 * 16 + c];
                float v2 = xx[(size_t)s2 * 16 + c];
                float v3 = xx[(size_t)s3 * 16 + c];
                acc = fmaf(v0, d0, acc);
                acc = fmaf(v1, d1, acc);
                acc = fmaf(v2, d2, acc);
                acc = fmaf(v3, d3, acc);
            }
            for (; j < jend; ++j) {
                int s = srt[j];
                acc = fmaf(xx[(size_t)s * 16 + c], dinv[s], acc);
            }

            float a = di * acc;

            // hidden layer: lane c computes units c and c+16
            float h0 = sb1[c], h1 = sb1[c + 16];
            #pragma unroll
            for (int kk = 0; kk < 16; ++kk) {
                float av = __shfl(a, kk, 16);
                h0 = fmaf(av, sWf[kk * 32 + c], h0);
                h1 = fmaf(av, sWf[kk * 32 + c + 16], h1);
            }
            h0 = fmaxf(h0, 0.f);
            h1 = fmaxf(h1, 0.f);

            float u = sb2[c];
            #pragma unroll
            for (int jj = 0; jj < 16; ++jj) {
                float hv0 = __shfl(h0, jj, 16);
                float hv1 = __shfl(h1, jj, 16);
                u = fmaf(hv0, sW2[jj * 16 + c], u);
                u = fmaf(hv1, sW2[(jj + 16) * 16 + c], u);
            }

            out[(size_t)node * 16 + c] = xv + u;
        }
    }
}

extern "C" void kernel_launch(void* const* d_in, const int* in_sizes, int n_in,
                              void* d_out, int out_size, void* d_ws, size_t ws_size,
                              hipStream_t stream) {
    const float* xx   = (const float*)d_in[0];
    const int*   edge = (const int*)d_in[1];   // [2, E]: row0 = src, row1 = dst
    const float* Wg   = (const float*)d_in[2];
    const float* W1   = (const float*)d_in[3];
    const float* b1   = (const float*)d_in[4];
    const float* W2   = (const float*)d_in[5];
    const float* b2   = (const float*)d_in[6];
    float* out = (float*)d_out;

    const int* srcI = edge;
    const int* dstI = edge + NEDGE;

    // workspace (4B words):
    // payload[NBUCKET*SEG = 8,497,946] | gcur[977] | dinv[500000] | Wf[512]
    // total = 8,999,435 words <= 9,000,512 available
    int*   ws      = (int*)d_ws;
    int*   payload = ws;
    int*   gcur    = ws + (size_t)NBUCKET * SEG;
    float* dinv    = (float*)(gcur + NBUCKET);
    float* Wf      = dinv + NNODE;

    // allow >64KB dynamic LDS for the staging scatter (one-time attribute set)
    static bool lds_attr_set = false;
    if (!lds_attr_set) {
        hipFuncSetAttribute((const void*)scatter_kernel,
                            hipFuncAttributeMaxDynamicSharedMemorySize,
                            SCATTER_LDS_BYTES);
        lds_attr_set = true;
    }

    hipLaunchKernelGGL(init_kernel, dim3(1), dim3(1024), 0, stream,
                       gcur, Wg, W1, Wf);

    hipLaunchKernelGGL(scatter_kernel, dim3(NBLK), dim3(1024), SCATTER_LDS_BYTES,
                       stream, srcI, dstI, gcur, payload);

    hipLaunchKernelGGL(dinv_kernel, dim3(NBUCKET), dim3(1024), 0, stream,
                       payload, gcur, dinv);

    hipLaunchKernelGGL(gather_kernel, dim3(NBUCKET), dim3(1024), 0, stream,
                       xx, payload, gcur, dinv, Wf, b1, W2, b2, out);
}